// Round 1
// baseline (1038.334 us; speedup 1.0000x reference)
//
#include <hip/hip_runtime.h>
#include <hip/hip_bf16.h>

#define HH 256
#define SSL 512
#define G3 768

using short8 = __attribute__((ext_vector_type(8))) short;
using f32x4  = __attribute__((ext_vector_type(4))) float;

__device__ __forceinline__ unsigned short f2bf(float f) {
  unsigned int u = __float_as_uint(f);
  u += 0x7FFFu + ((u >> 16) & 1u);
  return (unsigned short)(u >> 16);
}
__device__ __forceinline__ float bf2f(unsigned short b) {
  return __uint_as_float(((unsigned int)b) << 16);
}
// barrier that does NOT drain vmcnt (keeps global prefetch in flight)
__device__ __forceinline__ void block_sync_lds() {
  asm volatile("s_waitcnt lgkmcnt(0)\n\ts_barrier" ::: "memory");
}

// ---------------------------------------------------------------------------
// Prep: pack W_ih -> bf16 [j][k] rows; W_hh -> bf16 MFMA-fragment image.
// NEW 4-wave scan decomposition: F(w,g,mt,kt) = ((w*3+g)*4+mt)*8+kt,
// w in 0..3 (wave), g gate, mt 0..3 (16-row j tile), kt 0..7 (K=32 slice).
// row = g*256 + w*64 + mt*16 + (l&15); k0 = kt*32 + (l>>4)*8.
// ---------------------------------------------------------------------------
__global__ __launch_bounds__(256) void prep_pack(
    const float* __restrict__ Wih, const float* __restrict__ Whh,
    unsigned short* __restrict__ wih_bf, unsigned short* __restrict__ whh_frag)
{
  int blk = blockIdx.x;
  if (blk < 96) {
    int base = (blk * 256 + threadIdx.x) * 4;
#pragma unroll
    for (int i = 0; i < 4; i++) {
      int u = base + i;                      // 0..98303 u32-pairs
      float a = Wih[2 * u], b = Wih[2 * u + 1];
      ((unsigned int*)wih_bf)[u] = (unsigned int)f2bf(a) | ((unsigned int)f2bf(b) << 16);
    }
  } else {
    int gid = (blk - 96) * 256 + threadIdx.x;  // 0..24575
    int f = gid >> 6, l = gid & 63;
    int kt = f & 7, mt = (f >> 3) & 3, g = (f >> 5) % 3, w = f / 96;
    int row = g * HH + w * 64 + mt * 16 + (l & 15);
    int k0  = kt * 32 + (l >> 4) * 8;
    const float* src = Whh + (size_t)row * HH + k0;
    unsigned int o[4];
#pragma unroll
    for (int i = 0; i < 4; i++)
      o[i] = (unsigned int)f2bf(src[2 * i]) | ((unsigned int)f2bf(src[2 * i + 1]) << 16);
    *(uint4*)(whh_frag + ((size_t)f * 64 + l) * 8) = *(uint4*)o;
  }
}

// ---------------------------------------------------------------------------
// Kernel 1: GI[b][s][j] = sum_h X[b][h][s]*Wih[j][h] + bias[j]  (bf16 out)
// bias[j] = bih[j] + (j<512 ? bhh[j] : 0). (unchanged)
// ---------------------------------------------------------------------------
__global__ __launch_bounds__(512, 4) void gi_gemm(
    const float* __restrict__ X, const unsigned short* __restrict__ Wb,
    const float* __restrict__ bih, const float* __restrict__ bhh,
    unsigned short* __restrict__ gi)
{
  __shared__ __align__(16) char smem[36864];
  unsigned short* Al = (unsigned short*)smem;            // 128 rows x 64 shorts
  unsigned short* Bl = (unsigned short*)(smem + 16384);  // 128 rows x 64 shorts
  float (*Dl)[132] = (float(*)[132])smem;                // epilogue reuse

  const int tid  = threadIdx.x;
  const int lane = tid & 63;
  const int wave = tid >> 6;
  const int wm   = wave >> 2;
  const int wj   = wave & 3;
  const int n16  = lane & 15;
  const int quad = lane >> 4;

  const int mblk = blockIdx.y;
  const int b    = mblk >> 2;
  const int s0   = (mblk & 3) * 128;
  const int j0   = blockIdx.x * 128;

  f32x4 acc[4][2];
#pragma unroll
  for (int mt = 0; mt < 4; mt++)
#pragma unroll
    for (int jt = 0; jt < 2; jt++) acc[mt][jt] = f32x4{0.f, 0.f, 0.f, 0.f};

  const float* Xb = X + (size_t)b * (HH * SSL);

  float4 xa[2][2];   // [pass][h parity]
  uint4  wbv[2];     // B chunks

  auto ldA = [&](int kt, int q, float4* dst) {
    int idx = tid + 512 * q, sq = idx & 31, a = idx >> 5;
    const float* p = Xb + (size_t)(kt * 64 + 2 * a) * SSL + s0 + 4 * sq;
    dst[0] = *(const float4*)p;
    dst[1] = *(const float4*)(p + SSL);
  };
  auto ldB = [&](int kt, int q) -> uint4 {
    int cid = tid + 512 * q, j = cid >> 3, c = cid & 7;
    return *(const uint4*)(Wb + (size_t)(j0 + j) * HH + kt * 64 + c * 8);
  };

  ldA(0, 0, xa[0]); ldA(0, 1, xa[1]);
  wbv[0] = ldB(0, 0); wbv[1] = ldB(0, 1);

  for (int kt = 0; kt < 4; kt++) {
#pragma unroll
    for (int q = 0; q < 2; q++) {
      int idx = tid + 512 * q, sq = idx & 31, a = idx >> 5;
      int c = a >> 2, d = a & 3;
#pragma unroll
      for (int r = 0; r < 4; r++) {
        int s = 4 * sq + r;
        int sw = (s + (s >> 3)) & 7;
        unsigned int u =
            (unsigned int)f2bf(((const float*)&xa[q][0])[r]) |
            ((unsigned int)f2bf(((const float*)&xa[q][1])[r]) << 16);
        *(unsigned int*)(Al + s * 64 + ((c ^ sw) * 8) + d * 2) = u;
      }
    }
#pragma unroll
    for (int p = 0; p < 2; p++) {
      int cid = tid + 512 * p, j = cid >> 3, c = cid & 7;
      int sw = (j + (j >> 3)) & 7;
      *(uint4*)(Bl + j * 64 + ((c ^ sw) * 8)) = wbv[p];
    }
    __syncthreads();
    if (kt < 3) {
      ldA(kt + 1, 0, xa[0]); ldA(kt + 1, 1, xa[1]);
      wbv[0] = ldB(kt + 1, 0); wbv[1] = ldB(kt + 1, 1);
    }
#pragma unroll
    for (int kk = 0; kk < 2; kk++) {
      short8 af[4], bfr[2];
#pragma unroll
      for (int mt = 0; mt < 4; mt++) {
        int s = wm * 64 + mt * 16 + n16;
        int sw = (s + (s >> 3)) & 7;
        af[mt] = *(const short8*)(Al + s * 64 + (((kk * 4 + quad) ^ sw) * 8));
      }
#pragma unroll
      for (int jt = 0; jt < 2; jt++) {
        int j = wj * 32 + jt * 16 + n16;
        int sw = (j + (j >> 3)) & 7;
        bfr[jt] = *(const short8*)(Bl + j * 64 + (((kk * 4 + quad) ^ sw) * 8));
      }
#pragma unroll
      for (int mt = 0; mt < 4; mt++)
#pragma unroll
        for (int jt = 0; jt < 2; jt++)
          acc[mt][jt] = __builtin_amdgcn_mfma_f32_16x16x32_bf16(af[mt], bfr[jt], acc[mt][jt], 0, 0, 0);
    }
    __syncthreads();
  }

  float bias[2];
  {
    int jg0 = j0 + wj * 32 + 0 * 16 + n16;
    int jg1 = j0 + wj * 32 + 1 * 16 + n16;
    bias[0] = bih[jg0] + (jg0 < 2 * HH ? bhh[jg0] : 0.f);
    bias[1] = bih[jg1] + (jg1 < 2 * HH ? bhh[jg1] : 0.f);
  }

  for (int c = 0; c < 2; c++) {
    __syncthreads();
    if (wm == c) {
#pragma unroll
      for (int mt = 0; mt < 4; mt++)
#pragma unroll
        for (int jt = 0; jt < 2; jt++)
#pragma unroll
          for (int r = 0; r < 4; r++)
            Dl[mt * 16 + quad * 4 + r][wj * 32 + jt * 16 + n16] = acc[mt][jt][r] + bias[jt];
    }
    __syncthreads();
#pragma unroll
    for (int i = 0; i < 2; i++) {
      int ml = (tid >> 4) + 32 * i;
      int jj = (tid & 15) * 8;
      float4 p0 = *(const float4*)&Dl[ml][jj];
      float4 p1 = *(const float4*)&Dl[ml][jj + 4];
      short8 st;
      st[0] = (short)f2bf(p0.x); st[1] = (short)f2bf(p0.y);
      st[2] = (short)f2bf(p0.z); st[3] = (short)f2bf(p0.w);
      st[4] = (short)f2bf(p1.x); st[5] = (short)f2bf(p1.y);
      st[6] = (short)f2bf(p1.z); st[7] = (short)f2bf(p1.w);
      int sgl = s0 + c * 64 + ml;
      *(short8*)(gi + ((size_t)b * SSL + sgl) * G3 + j0 + jj) = st;
    }
  }
}

// ---------------------------------------------------------------------------
// Kernel 2: persistent GRU scan. 64 blocks x 4 rows, 256 thr (4 waves,
// 1 wave/SIMD => 512-reg unified budget per wave).
// R6 theory: the 8-wave version was LDS-pipe-bound (192 ds_read_b128/step:
// hb re-read per mt (16x) + w2 spills = ~2300cy of the ~3330cy step). With
// 4 waves each hb read feeds 24 MFMAs; all 96 W frags/wave live in regs
// (64 "+a" AGPR + 32 "+v" VGPR), hb hoisted once per step => 32 reads/step
// per CU (~380cy) < MFMA pipe (96 MFMA/SIMD ~480cy). MFMAs paired across
// two mt tiles (6 independent chains) to cover dep latency at 1 wave/SIMD.
// hbuf uses 17-slot padded kt stride so h-writes don't 8-way conflict.
// ---------------------------------------------------------------------------
__global__ __launch_bounds__(256, 1) void gru_scan(
    const float* __restrict__ tree, const int* __restrict__ mask,
    const unsigned short* __restrict__ wfrag, const float* __restrict__ bhh,
    const unsigned short* __restrict__ gi, float* __restrict__ out)
{
  // slot(kt,b,q) = kt*17 + b*4 + q (16B units); pad => write ~4-way, read free
  __shared__ __align__(16) unsigned short hbuf[2][1088];
  __shared__ __align__(16) float preF[3][4][264];
  __shared__ int lsum[4];

  const int tid  = threadIdx.x;
  const int lane = tid & 63;
  const int w    = tid >> 6;        // wave id == batch row in phase B
  const int n16  = lane & 15;
  const int quad = lane >> 4;
  const int brow0 = blockIdx.x * 4;
  const int jj   = lane * 4;        // 4 h elements per thread

  if (tid < 4) lsum[tid] = 0;

  // initial h -> hbuf[0]
  f32x4 h4 = *(const f32x4*)(tree + (size_t)(brow0 + w) * HH + jj);
  float h0 = h4[0], h1 = h4[1], h2 = h4[2], h3 = h4[3];
  const int wslot = ((jj >> 5) * 17 + w * 4 + ((jj >> 3) & 3)) * 8 + (jj & 7);
  {
    unsigned long long u =
        (unsigned long long)((unsigned)f2bf(h0) | ((unsigned)f2bf(h1) << 16)) |
        ((unsigned long long)((unsigned)f2bf(h2) | ((unsigned)f2bf(h3) << 16)) << 32);
    *(unsigned long long*)&hbuf[0][wslot] = u;
  }
  __syncthreads();
  {
    const int* mp = mask + (size_t)(brow0 + w) * SSL + lane * 8;
    int4 a = *(const int4*)mp;
    int4 b = *(const int4*)(mp + 4);
    atomicAdd(&lsum[w], a.x + a.y + a.z + a.w + b.x + b.y + b.z + b.w);
  }

  // W fragments: g=0,1 -> AGPR (64 frags = 256 AGPR); g=2 -> VGPR (128 VGPR)
  short8 awA[2][4][8];
  short8 awV[4][8];
#pragma unroll
  for (int g = 0; g < 2; g++)
#pragma unroll
    for (int mt = 0; mt < 4; mt++)
#pragma unroll
      for (int kt = 0; kt < 8; kt++) {
        int F = ((w * 3 + g) * 4 + mt) * 8 + kt;
        awA[g][mt][kt] = *(const short8*)(wfrag + ((size_t)F * 64 + lane) * 8);
      }
#pragma unroll
  for (int mt = 0; mt < 4; mt++)
#pragma unroll
    for (int kt = 0; kt < 8; kt++) {
      int F = ((w * 3 + 2) * 4 + mt) * 8 + kt;
      awV[mt][kt] = *(const short8*)(wfrag + ((size_t)F * 64 + lane) * 8);
    }
  // Pin: opaque to remat; forces register class. (R5 lesson: without pins the
  // allocator re-loads W from L2 every step.)
#pragma unroll
  for (int g = 0; g < 2; g++)
#pragma unroll
    for (int mt = 0; mt < 4; mt++)
#pragma unroll
      for (int kt = 0; kt < 8; kt++)
        asm volatile("" : "+a"(awA[g][mt][kt]));
#pragma unroll
  for (int mt = 0; mt < 4; mt++)
#pragma unroll
    for (int kt = 0; kt < 8; kt++)
      asm volatile("" : "+v"(awV[mt][kt]));

  f32x4 bh4 = *(const f32x4*)(bhh + 2 * HH + jj);

  const unsigned short* gib = gi + (size_t)(brow0 + w) * SSL * G3 + jj;
  unsigned long long gA[3], gB[3];
#pragma unroll
  for (int g = 0; g < 3; g++) gA[g] = *(const unsigned long long*)(gib + (size_t)0 * G3 + g * HH);
#pragma unroll
  for (int g = 0; g < 3; g++) gB[g] = *(const unsigned long long*)(gib + (size_t)1 * G3 + g * HH);

  __syncthreads();
  int last = lsum[w] - 1; if (last < 0) last = 0;

  auto step = [&](int t, unsigned long long* gv) {
    const int cb = t & 1, nb = cb ^ 1;
    // save current gi words before prefetch overwrites them
    unsigned long long g0 = gv[0], g1 = gv[1], g2 = gv[2];

    // ---- phase A: hb hoisted (8 reads/wave/step), 96 MFMAs from registers ----
    const unsigned short* hp = &hbuf[cb][0] + ((n16 & 3) * 4 + quad) * 8;
    short8 hb[8];
#pragma unroll
    for (int kt = 0; kt < 8; kt++)
      hb[kt] = *(const short8*)(hp + kt * (17 * 8));

    // prefetch gi for t+2 early: overlaps the MFMA phase; barrier keeps vmcnt
    int tn = (t + 2 < SSL) ? t + 2 : SSL - 1;
    gv[0] = *(const unsigned long long*)(gib + (size_t)tn * G3 + 0 * HH);
    gv[1] = *(const unsigned long long*)(gib + (size_t)tn * G3 + 1 * HH);
    gv[2] = *(const unsigned long long*)(gib + (size_t)tn * G3 + 2 * HH);

#pragma unroll
    for (int mp = 0; mp < 2; mp++) {
      const int m0 = 2 * mp, m1 = 2 * mp + 1;
      f32x4 ar0 = f32x4{0.f, 0.f, 0.f, 0.f}, az0 = ar0, an0 = ar0;
      f32x4 ar1 = ar0, az1 = ar0, an1 = ar0;
#pragma unroll
      for (int kt = 0; kt < 8; kt++) {
        ar0 = __builtin_amdgcn_mfma_f32_16x16x32_bf16(awA[0][m0][kt], hb[kt], ar0, 0, 0, 0);
        ar1 = __builtin_amdgcn_mfma_f32_16x16x32_bf16(awA[0][m1][kt], hb[kt], ar1, 0, 0, 0);
        az0 = __builtin_amdgcn_mfma_f32_16x16x32_bf16(awA[1][m0][kt], hb[kt], az0, 0, 0, 0);
        az1 = __builtin_amdgcn_mfma_f32_16x16x32_bf16(awA[1][m1][kt], hb[kt], az1, 0, 0, 0);
        an0 = __builtin_amdgcn_mfma_f32_16x16x32_bf16(awV[m0][kt],    hb[kt], an0, 0, 0, 0);
        an1 = __builtin_amdgcn_mfma_f32_16x16x32_bf16(awV[m1][kt],    hb[kt], an1, 0, 0, 0);
      }
      if (n16 < 4) {
        int r0 = w * 64 + m0 * 16 + quad * 4;
        int r1 = w * 64 + m1 * 16 + quad * 4;
        *(f32x4*)&preF[0][n16][r0] = ar0;
        *(f32x4*)&preF[0][n16][r1] = ar1;
        *(f32x4*)&preF[1][n16][r0] = az0;
        *(f32x4*)&preF[1][n16][r1] = az1;
        *(f32x4*)&preF[2][n16][r0] = an0;
        *(f32x4*)&preF[2][n16][r1] = an1;
      }
    }
    block_sync_lds();

    // ---- phase B: wave w owns batch row w; jj = lane*4 h-elements ----
    f32x4 pr = *(const f32x4*)&preF[0][w][jj];
    f32x4 pz = *(const f32x4*)&preF[1][w][jj];
    f32x4 pn = *(const f32x4*)&preF[2][w][jj];

    float hv[4] = {h0, h1, h2, h3};
#pragma unroll
    for (int e = 0; e < 4; e++) {
      float gr = bf2f((unsigned short)((g0 >> (16 * e)) & 0xFFFFull));
      float gz = bf2f((unsigned short)((g1 >> (16 * e)) & 0xFFFFull));
      float gn = bf2f((unsigned short)((g2 >> (16 * e)) & 0xFFFFull));
      float r = __builtin_amdgcn_rcpf(1.f + __expf(-(pr[e] + gr)));
      float z = __builtin_amdgcn_rcpf(1.f + __expf(-(pz[e] + gz)));
      float a = gn + r * (pn[e] + bh4[e]);
      float nn = 1.f - 2.f * __builtin_amdgcn_rcpf(__expf(2.f * a) + 1.f);
      hv[e] = nn + z * (hv[e] - nn);
    }
    h0 = hv[0]; h1 = hv[1]; h2 = hv[2]; h3 = hv[3];
    {
      unsigned long long u =
          (unsigned long long)((unsigned)f2bf(h0) | ((unsigned)f2bf(h1) << 16)) |
          ((unsigned long long)((unsigned)f2bf(h2) | ((unsigned)f2bf(h3) << 16)) << 32);
      *(unsigned long long*)&hbuf[nb][wslot] = u;
    }
    if (t == last) {   // wave-uniform branch
      f32x4 o = {h0, h1, h2, h3};
      *(f32x4*)(out + (size_t)(brow0 + w) * HH + jj) = o;
    }
    block_sync_lds();
  };

  for (int t = 0; t < SSL; t += 2) {
    step(t, gA);
    step(t + 1, gB);
  }
}

extern "C" void kernel_launch(void* const* d_in, const int* in_sizes, int n_in,
                              void* d_out, int out_size, void* d_ws, size_t ws_size,
                              hipStream_t stream) {
  const float* tree = (const float*)d_in[0];
  const float* seq  = (const float*)d_in[1];
  const int*   mask = (const int*)d_in[2];
  const float* Wih  = (const float*)d_in[3];
  const float* Whh  = (const float*)d_in[4];
  const float* bih  = (const float*)d_in[5];
  const float* bhh  = (const float*)d_in[6];
  float* out = (float*)d_out;

  unsigned short* gi      = (unsigned short*)d_ws;                       // 201,326,592 B
  unsigned short* wih_bf  = (unsigned short*)((char*)d_ws + 201326592);  // 393,216 B
  unsigned short* whh_frag= (unsigned short*)((char*)d_ws + 201719808);  // 393,216 B

  prep_pack<<<192, 256, 0, stream>>>(Wih, Whh, wih_bf, whh_frag);
  gi_gemm<<<dim3(6, 1024), 512, 0, stream>>>(seq, wih_bf, bih, bhh, gi);
  gru_scan<<<64, 256, 0, stream>>>(tree, mask, whh_frag, bhh, gi, out);
}

// Round 2
// 912.489 us; speedup vs baseline: 1.1379x; 1.1379x over previous
//
#include <hip/hip_runtime.h>
#include <hip/hip_bf16.h>

#define HH 256
#define SSL 512
#define G3 768

using short8 = __attribute__((ext_vector_type(8))) short;
using f32x4  = __attribute__((ext_vector_type(4))) float;

__device__ __forceinline__ unsigned short f2bf(float f) {
  unsigned int u = __float_as_uint(f);
  u += 0x7FFFu + ((u >> 16) & 1u);
  return (unsigned short)(u >> 16);
}
__device__ __forceinline__ float bf2f(unsigned short b) {
  return __uint_as_float(((unsigned int)b) << 16);
}
// m201-pattern end-of-step sync: targeted lgkm drain, raw barrier, sched pin.
// No vmcnt drain -> global prefetch stays in flight across the barrier.
__device__ __forceinline__ void sync_step() {
  asm volatile("s_waitcnt lgkmcnt(0)" ::: "memory");
  __builtin_amdgcn_s_barrier();
  __builtin_amdgcn_sched_barrier(0);
}

// ---------------------------------------------------------------------------
// Prep: pack W_ih -> bf16 [j][k] rows; W_hh -> bf16 MFMA-fragment image.
// F(w,g,mt,kt) = ((w*3+g)*4+mt)*8+kt, w=wave, g gate, mt 16-row tile, kt K=32.
// row = g*256 + w*64 + mt*16 + (l&15); k0 = kt*32 + (l>>4)*8.
// ---------------------------------------------------------------------------
__global__ __launch_bounds__(256) void prep_pack(
    const float* __restrict__ Wih, const float* __restrict__ Whh,
    unsigned short* __restrict__ wih_bf, unsigned short* __restrict__ whh_frag)
{
  int blk = blockIdx.x;
  if (blk < 96) {
    int base = (blk * 256 + threadIdx.x) * 4;
#pragma unroll
    for (int i = 0; i < 4; i++) {
      int u = base + i;                      // 0..98303 u32-pairs
      float a = Wih[2 * u], b = Wih[2 * u + 1];
      ((unsigned int*)wih_bf)[u] = (unsigned int)f2bf(a) | ((unsigned int)f2bf(b) << 16);
    }
  } else {
    int gid = (blk - 96) * 256 + threadIdx.x;  // 0..24575
    int f = gid >> 6, l = gid & 63;
    int kt = f & 7, mt = (f >> 3) & 3, g = (f >> 5) % 3, w = f / 96;
    int row = g * HH + w * 64 + mt * 16 + (l & 15);
    int k0  = kt * 32 + (l >> 4) * 8;
    const float* src = Whh + (size_t)row * HH + k0;
    unsigned int o[4];
#pragma unroll
    for (int i = 0; i < 4; i++)
      o[i] = (unsigned int)f2bf(src[2 * i]) | ((unsigned int)f2bf(src[2 * i + 1]) << 16);
    *(uint4*)(whh_frag + ((size_t)f * 64 + l) * 8) = *(uint4*)o;
  }
}

// ---------------------------------------------------------------------------
// Kernel 1: GI[b][s][j] = sum_h X[b][h][s]*Wih[j][h] + bias[j]  (bf16 out)
// bias[j] = bih[j] + (j<512 ? bhh[j] : 0). (unchanged)
// ---------------------------------------------------------------------------
__global__ __launch_bounds__(512, 4) void gi_gemm(
    const float* __restrict__ X, const unsigned short* __restrict__ Wb,
    const float* __restrict__ bih, const float* __restrict__ bhh,
    unsigned short* __restrict__ gi)
{
  __shared__ __align__(16) char smem[36864];
  unsigned short* Al = (unsigned short*)smem;            // 128 rows x 64 shorts
  unsigned short* Bl = (unsigned short*)(smem + 16384);  // 128 rows x 64 shorts
  float (*Dl)[132] = (float(*)[132])smem;                // epilogue reuse

  const int tid  = threadIdx.x;
  const int lane = tid & 63;
  const int wave = tid >> 6;
  const int wm   = wave >> 2;
  const int wj   = wave & 3;
  const int n16  = lane & 15;
  const int quad = lane >> 4;

  const int mblk = blockIdx.y;
  const int b    = mblk >> 2;
  const int s0   = (mblk & 3) * 128;
  const int j0   = blockIdx.x * 128;

  f32x4 acc[4][2];
#pragma unroll
  for (int mt = 0; mt < 4; mt++)
#pragma unroll
    for (int jt = 0; jt < 2; jt++) acc[mt][jt] = f32x4{0.f, 0.f, 0.f, 0.f};

  const float* Xb = X + (size_t)b * (HH * SSL);

  float4 xa[2][2];   // [pass][h parity]
  uint4  wbv[2];     // B chunks

  auto ldA = [&](int kt, int q, float4* dst) {
    int idx = tid + 512 * q, sq = idx & 31, a = idx >> 5;
    const float* p = Xb + (size_t)(kt * 64 + 2 * a) * SSL + s0 + 4 * sq;
    dst[0] = *(const float4*)p;
    dst[1] = *(const float4*)(p + SSL);
  };
  auto ldB = [&](int kt, int q) -> uint4 {
    int cid = tid + 512 * q, j = cid >> 3, c = cid & 7;
    return *(const uint4*)(Wb + (size_t)(j0 + j) * HH + kt * 64 + c * 8);
  };

  ldA(0, 0, xa[0]); ldA(0, 1, xa[1]);
  wbv[0] = ldB(0, 0); wbv[1] = ldB(0, 1);

  for (int kt = 0; kt < 4; kt++) {
#pragma unroll
    for (int q = 0; q < 2; q++) {
      int idx = tid + 512 * q, sq = idx & 31, a = idx >> 5;
      int c = a >> 2, d = a & 3;
#pragma unroll
      for (int r = 0; r < 4; r++) {
        int s = 4 * sq + r;
        int sw = (s + (s >> 3)) & 7;
        unsigned int u =
            (unsigned int)f2bf(((const float*)&xa[q][0])[r]) |
            ((unsigned int)f2bf(((const float*)&xa[q][1])[r]) << 16);
        *(unsigned int*)(Al + s * 64 + ((c ^ sw) * 8) + d * 2) = u;
      }
    }
#pragma unroll
    for (int p = 0; p < 2; p++) {
      int cid = tid + 512 * p, j = cid >> 3, c = cid & 7;
      int sw = (j + (j >> 3)) & 7;
      *(uint4*)(Bl + j * 64 + ((c ^ sw) * 8)) = wbv[p];
    }
    __syncthreads();
    if (kt < 3) {
      ldA(kt + 1, 0, xa[0]); ldA(kt + 1, 1, xa[1]);
      wbv[0] = ldB(kt + 1, 0); wbv[1] = ldB(kt + 1, 1);
    }
#pragma unroll
    for (int kk = 0; kk < 2; kk++) {
      short8 af[4], bfr[2];
#pragma unroll
      for (int mt = 0; mt < 4; mt++) {
        int s = wm * 64 + mt * 16 + n16;
        int sw = (s + (s >> 3)) & 7;
        af[mt] = *(const short8*)(Al + s * 64 + (((kk * 4 + quad) ^ sw) * 8));
      }
#pragma unroll
      for (int jt = 0; jt < 2; jt++) {
        int j = wj * 32 + jt * 16 + n16;
        int sw = (j + (j >> 3)) & 7;
        bfr[jt] = *(const short8*)(Bl + j * 64 + (((kk * 4 + quad) ^ sw) * 8));
      }
#pragma unroll
      for (int mt = 0; mt < 4; mt++)
#pragma unroll
        for (int jt = 0; jt < 2; jt++)
          acc[mt][jt] = __builtin_amdgcn_mfma_f32_16x16x32_bf16(af[mt], bfr[jt], acc[mt][jt], 0, 0, 0);
    }
    __syncthreads();
  }

  float bias[2];
  {
    int jg0 = j0 + wj * 32 + 0 * 16 + n16;
    int jg1 = j0 + wj * 32 + 1 * 16 + n16;
    bias[0] = bih[jg0] + (jg0 < 2 * HH ? bhh[jg0] : 0.f);
    bias[1] = bih[jg1] + (jg1 < 2 * HH ? bhh[jg1] : 0.f);
  }

  for (int c = 0; c < 2; c++) {
    __syncthreads();
    if (wm == c) {
#pragma unroll
      for (int mt = 0; mt < 4; mt++)
#pragma unroll
        for (int jt = 0; jt < 2; jt++)
#pragma unroll
          for (int r = 0; r < 4; r++)
            Dl[mt * 16 + quad * 4 + r][wj * 32 + jt * 16 + n16] = acc[mt][jt][r] + bias[jt];
    }
    __syncthreads();
#pragma unroll
    for (int i = 0; i < 2; i++) {
      int ml = (tid >> 4) + 32 * i;
      int jj = (tid & 15) * 8;
      float4 p0 = *(const float4*)&Dl[ml][jj];
      float4 p1 = *(const float4*)&Dl[ml][jj + 4];
      short8 st;
      st[0] = (short)f2bf(p0.x); st[1] = (short)f2bf(p0.y);
      st[2] = (short)f2bf(p0.z); st[3] = (short)f2bf(p0.w);
      st[4] = (short)f2bf(p1.x); st[5] = (short)f2bf(p1.y);
      st[6] = (short)f2bf(p1.z); st[7] = (short)f2bf(p1.w);
      int sgl = s0 + c * 64 + ml;
      *(short8*)(gi + ((size_t)b * SSL + sgl) * G3 + j0 + jj) = st;
    }
  }
}

// ---------------------------------------------------------------------------
// Kernel 2: persistent GRU scan. 64 blocks x 4 rows, 256 thr, 1 wave/SIMD.
// R7: in-register gates via the replica-lane trick. MFMA C-layout gives
// gh[j][batch] with batch columns replicated 4x across n16 (cols 4..15 copy
// 0..3). Lane (b=n16&3, rep=n16>>2, quad) takes the mt=rep tile: cndmask-
// select acc -> gates computed in-lane, h_old lane-resident. Deletes the
// preF LDS round-trip AND one barrier+lgkm drain per step (R6 post-mortem:
// step time invariant at ~3400cy across LDS-traffic/occupancy changes =>
// latency-chain-bound; this removes ~2 of the 4 chain segments).
// Only h-broadcast (cross-wave k-exchange) keeps 1 LDS round-trip/step.
// ---------------------------------------------------------------------------
__global__ __launch_bounds__(256, 1) void gru_scan(
    const float* __restrict__ tree, const int* __restrict__ mask,
    const unsigned short* __restrict__ wfrag, const float* __restrict__ bhh,
    const unsigned short* __restrict__ gi, float* __restrict__ out)
{
  // slot(kt,b,q) = kt*17 + b*4 + q (16B units); 17-pad spreads banks
  __shared__ __align__(16) unsigned short hbuf[2][1088];
  __shared__ int lsum[4];

  const int tid  = threadIdx.x;
  const int lane = tid & 63;
  const int w    = tid >> 6;
  const int n16  = lane & 15;
  const int quad = lane >> 4;
  const int b    = n16 & 3;          // batch row owned by this lane
  const int rep  = n16 >> 2;         // replica index -> owns mt tile = rep
  const int brow0 = blockIdx.x * 4;
  const int jbase = w * 64 + rep * 16 + quad * 4;  // 4 owned j's

  if (tid < 4) lsum[tid] = 0;

  // initial h (lane-resident, f32)
  f32x4 h4 = *(const f32x4*)(tree + (size_t)(brow0 + b) * HH + jbase);

  // h write slot: kt=jbase>>5, q=(jbase>>3)&3, half=(quad&1)*4
  const int wslot = ((w * 2 + (rep >> 1)) * 17 + b * 4 + ((rep & 1) * 2 + (quad >> 1))) * 8
                  + (quad & 1) * 4;
  {
    unsigned long long u =
        (unsigned long long)((unsigned)f2bf(h4[0]) | ((unsigned)f2bf(h4[1]) << 16)) |
        ((unsigned long long)((unsigned)f2bf(h4[2]) | ((unsigned)f2bf(h4[3]) << 16)) << 32);
    *(unsigned long long*)&hbuf[0][wslot] = u;
  }
  {
    const int* mp = mask + (size_t)(brow0 + w) * SSL + lane * 8;
    int4 a = *(const int4*)mp;
    int4 c = *(const int4*)(mp + 4);
    atomicAdd(&lsum[w], a.x + a.y + a.z + a.w + c.x + c.y + c.z + c.w);
  }

  // W fragments: g=0,1 -> AGPR (64 frags = 256 AGPR); g=2 -> VGPR (128 VGPR)
  short8 awA[2][4][8];
  short8 awV[4][8];
#pragma unroll
  for (int g = 0; g < 2; g++)
#pragma unroll
    for (int mt = 0; mt < 4; mt++)
#pragma unroll
      for (int kt = 0; kt < 8; kt++) {
        int F = ((w * 3 + g) * 4 + mt) * 8 + kt;
        awA[g][mt][kt] = *(const short8*)(wfrag + ((size_t)F * 64 + lane) * 8);
      }
#pragma unroll
  for (int mt = 0; mt < 4; mt++)
#pragma unroll
    for (int kt = 0; kt < 8; kt++) {
      int F = ((w * 3 + 2) * 4 + mt) * 8 + kt;
      awV[mt][kt] = *(const short8*)(wfrag + ((size_t)F * 64 + lane) * 8);
    }
  // Pin: opaque to remat; forces register class (R5 lesson).
#pragma unroll
  for (int g = 0; g < 2; g++)
#pragma unroll
    for (int mt = 0; mt < 4; mt++)
#pragma unroll
      for (int kt = 0; kt < 8; kt++)
        asm volatile("" : "+a"(awA[g][mt][kt]));
#pragma unroll
  for (int mt = 0; mt < 4; mt++)
#pragma unroll
    for (int kt = 0; kt < 8; kt++)
      asm volatile("" : "+v"(awV[mt][kt]));

  f32x4 bh4 = *(const f32x4*)(bhh + 2 * HH + jbase);

  // per-lane gi stream: batch row b, j's = jbase..jbase+3, 3 gates (8B each)
  const unsigned short* gip = gi + (size_t)(brow0 + b) * SSL * G3 + jbase;
  unsigned long long gA[3], gB[3];
#pragma unroll
  for (int g = 0; g < 3; g++) gA[g] = *(const unsigned long long*)(gip + (size_t)0 * G3 + g * HH);
#pragma unroll
  for (int g = 0; g < 3; g++) gB[g] = *(const unsigned long long*)(gip + (size_t)1 * G3 + g * HH);

  __syncthreads();
  int mylast = lsum[b] - 1; if (mylast < 0) mylast = 0;

  auto step = [&](int t, unsigned long long* gv) {
    const int cb = t & 1, nb = cb ^ 1;
    unsigned long long g0 = gv[0], g1 = gv[1], g2 = gv[2];

    // hb fragments first (starts LDS latency early)
    const unsigned short* hp = &hbuf[cb][0] + ((n16 & 3) * 4 + quad) * 8;
    short8 hb[8];
#pragma unroll
    for (int kt = 0; kt < 8; kt++)
      hb[kt] = *(const short8*)(hp + kt * (17 * 8));

    // prefetch gi for t+2 (covered by ~1 full step; no vmcnt drain at barrier)
    int tn = (t + 2 < SSL) ? t + 2 : SSL - 1;
    gv[0] = *(const unsigned long long*)(gip + (size_t)tn * G3 + 0 * HH);
    gv[1] = *(const unsigned long long*)(gip + (size_t)tn * G3 + 1 * HH);
    gv[2] = *(const unsigned long long*)(gip + (size_t)tn * G3 + 2 * HH);

    // ---- MFMA: 96 per wave, 6 independent chains per pass; select own tile ----
    f32x4 selR, selZ, selN;
#pragma unroll
    for (int mp = 0; mp < 2; mp++) {
      const int m0 = 2 * mp, m1 = 2 * mp + 1;
      f32x4 ar0 = f32x4{0.f, 0.f, 0.f, 0.f}, az0 = ar0, an0 = ar0;
      f32x4 ar1 = ar0, az1 = ar0, an1 = ar0;
#pragma unroll
      for (int kt = 0; kt < 8; kt++) {
        ar0 = __builtin_amdgcn_mfma_f32_16x16x32_bf16(awA[0][m0][kt], hb[kt], ar0, 0, 0, 0);
        ar1 = __builtin_amdgcn_mfma_f32_16x16x32_bf16(awA[0][m1][kt], hb[kt], ar1, 0, 0, 0);
        az0 = __builtin_amdgcn_mfma_f32_16x16x32_bf16(awA[1][m0][kt], hb[kt], az0, 0, 0, 0);
        az1 = __builtin_amdgcn_mfma_f32_16x16x32_bf16(awA[1][m1][kt], hb[kt], az1, 0, 0, 0);
        an0 = __builtin_amdgcn_mfma_f32_16x16x32_bf16(awV[m0][kt],    hb[kt], an0, 0, 0, 0);
        an1 = __builtin_amdgcn_mfma_f32_16x16x32_bf16(awV[m1][kt],    hb[kt], an1, 0, 0, 0);
      }
      if (mp == 0) {
        selR = (rep == 0) ? ar0 : ar1;   // rep 2,3 garbage, fixed next pass
        selZ = (rep == 0) ? az0 : az1;
        selN = (rep == 0) ? an0 : an1;
      } else {
        selR = (rep == 2) ? ar0 : ((rep == 3) ? ar1 : selR);
        selZ = (rep == 2) ? az0 : ((rep == 3) ? az1 : selZ);
        selN = (rep == 2) ? an0 : ((rep == 3) ? an1 : selN);
      }
    }

    // ---- gates in-register: 4 (j,b) elements per lane ----
#pragma unroll
    for (int e = 0; e < 4; e++) {
      float gr = bf2f((unsigned short)((g0 >> (16 * e)) & 0xFFFFull));
      float gz = bf2f((unsigned short)((g1 >> (16 * e)) & 0xFFFFull));
      float gn = bf2f((unsigned short)((g2 >> (16 * e)) & 0xFFFFull));
      float r = __builtin_amdgcn_rcpf(1.f + __expf(-(selR[e] + gr)));
      float z = __builtin_amdgcn_rcpf(1.f + __expf(-(selZ[e] + gz)));
      float a = gn + r * (selN[e] + bh4[e]);
      float nn = 1.f - 2.f * __builtin_amdgcn_rcpf(__expf(2.f * a) + 1.f);
      h4[e] = nn + z * (h4[e] - nn);
    }
    {
      unsigned long long u =
          (unsigned long long)((unsigned)f2bf(h4[0]) | ((unsigned)f2bf(h4[1]) << 16)) |
          ((unsigned long long)((unsigned)f2bf(h4[2]) | ((unsigned)f2bf(h4[3]) << 16)) << 32);
      *(unsigned long long*)&hbuf[nb][wslot] = u;
    }
    if (t == mylast) {   // per-lane predicate (last unmasked timestep of batch b)
      *(f32x4*)(out + (size_t)(brow0 + b) * HH + jbase) = h4;
    }
    sync_step();
  };

  for (int t = 0; t < SSL; t += 2) {
    step(t, gA);
    step(t + 1, gB);
  }
}

extern "C" void kernel_launch(void* const* d_in, const int* in_sizes, int n_in,
                              void* d_out, int out_size, void* d_ws, size_t ws_size,
                              hipStream_t stream) {
  const float* tree = (const float*)d_in[0];
  const float* seq  = (const float*)d_in[1];
  const int*   mask = (const int*)d_in[2];
  const float* Wih  = (const float*)d_in[3];
  const float* Whh  = (const float*)d_in[4];
  const float* bih  = (const float*)d_in[5];
  const float* bhh  = (const float*)d_in[6];
  float* out = (float*)d_out;

  unsigned short* gi      = (unsigned short*)d_ws;                       // 201,326,592 B
  unsigned short* wih_bf  = (unsigned short*)((char*)d_ws + 201326592);  // 393,216 B
  unsigned short* whh_frag= (unsigned short*)((char*)d_ws + 201719808);  // 393,216 B

  prep_pack<<<192, 256, 0, stream>>>(Wih, Whh, wih_bf, whh_frag);
  gi_gemm<<<dim3(6, 1024), 512, 0, stream>>>(seq, wih_bf, bih, bhh, gi);
  gru_scan<<<64, 256, 0, stream>>>(tree, mask, whh_frag, bhh, gi, out);
}

// Round 3
// 874.177 us; speedup vs baseline: 1.1878x; 1.0438x over previous
//
#include <hip/hip_runtime.h>
#include <hip/hip_bf16.h>

#define HH 256
#define SSL 512
#define G3 768

using short8 = __attribute__((ext_vector_type(8))) short;
using f32x4  = __attribute__((ext_vector_type(4))) float;

__device__ __forceinline__ unsigned short f2bf(float f) {
  unsigned int u = __float_as_uint(f);
  u += 0x7FFFu + ((u >> 16) & 1u);
  return (unsigned short)(u >> 16);
}
__device__ __forceinline__ float bf2f(unsigned short b) {
  return __uint_as_float(((unsigned int)b) << 16);
}
// m201-pattern end-of-step sync: targeted lgkm drain, raw barrier, sched pin.
// No vmcnt drain -> global prefetch stays in flight across the barrier.
__device__ __forceinline__ void sync_step() {
  asm volatile("s_waitcnt lgkmcnt(0)" ::: "memory");
  __builtin_amdgcn_s_barrier();
  __builtin_amdgcn_sched_barrier(0);
}

// ---------------------------------------------------------------------------
// Prep: pack W_ih -> bf16 [j][k] rows; W_hh -> bf16 MFMA-fragment image.
// F(w,g,mt,kt) = ((w*3+g)*4+mt)*8+kt, w=wave, g gate, mt 16-row tile, kt K=32.
// row = g*256 + w*64 + mt*16 + (l&15); k0 = kt*32 + (l>>4)*8.
// ---------------------------------------------------------------------------
__global__ __launch_bounds__(256) void prep_pack(
    const float* __restrict__ Wih, const float* __restrict__ Whh,
    unsigned short* __restrict__ wih_bf, unsigned short* __restrict__ whh_frag)
{
  int blk = blockIdx.x;
  if (blk < 96) {
    int base = (blk * 256 + threadIdx.x) * 4;
#pragma unroll
    for (int i = 0; i < 4; i++) {
      int u = base + i;                      // 0..98303 u32-pairs
      float a = Wih[2 * u], b = Wih[2 * u + 1];
      ((unsigned int*)wih_bf)[u] = (unsigned int)f2bf(a) | ((unsigned int)f2bf(b) << 16);
    }
  } else {
    int gid = (blk - 96) * 256 + threadIdx.x;  // 0..24575
    int f = gid >> 6, l = gid & 63;
    int kt = f & 7, mt = (f >> 3) & 3, g = (f >> 5) % 3, w = f / 96;
    int row = g * HH + w * 64 + mt * 16 + (l & 15);
    int k0  = kt * 32 + (l >> 4) * 8;
    const float* src = Whh + (size_t)row * HH + k0;
    unsigned int o[4];
#pragma unroll
    for (int i = 0; i < 4; i++)
      o[i] = (unsigned int)f2bf(src[2 * i]) | ((unsigned int)f2bf(src[2 * i + 1]) << 16);
    *(uint4*)(whh_frag + ((size_t)f * 64 + l) * 8) = *(uint4*)o;
  }
}

// ---------------------------------------------------------------------------
// Kernel 1 (R8 rework): GI[b][s][j] = sum_h X[b][h][s]*Wih[j][h] + bias[j].
// One block per 128-s tile (1024 blocks); FULL K=256 staged once in LDS
// (transpose+bf16-convert fused, swizzled); loop all 6 j-tiles per block.
// X read ONCE from HBM (was 6x = 786MB L3 traffic); W re-reads are L2-hits.
// A-fragments hoisted to regs (af[4][8] = 128 VGPR) and reused for all jb.
// LDS: A 64K + B 64K + Dl(bf16) 17K + bias 3K = 148.5K -> 1 block/CU.
// ---------------------------------------------------------------------------
__global__ __launch_bounds__(512, 2) void gi_gemm(
    const float* __restrict__ X, const unsigned short* __restrict__ Wb,
    const float* __restrict__ bih, const float* __restrict__ bhh,
    unsigned short* __restrict__ gi)
{
  __shared__ __align__(16) unsigned short Al[128 * 256];  // [s][256h], swizzled per 64-slice
  __shared__ __align__(16) unsigned short Bl[128 * 256];  // [j][256k], swizzled per 64-slice
  __shared__ __align__(16) unsigned short Dl[64][136];    // bf16 epilogue staging
  __shared__ float biasl[G3];

  const int tid  = threadIdx.x;
  const int lane = tid & 63;
  const int wave = tid >> 6;
  const int wm   = wave >> 2;   // 0..1: M half (64 s-rows)
  const int wn   = wave & 3;    // 0..3: N quarter (32 j-cols)
  const int n16  = lane & 15;
  const int quad = lane >> 4;

  const int mblk = blockIdx.x;
  const int b    = mblk >> 2;
  const int s0   = (mblk & 3) * 128;

  const float* Xb = X + (size_t)b * (HH * SSL);

  // bias to LDS: bias[j] = bih[j] + (j<512 ? bhh[j] : 0)
  for (int i = tid; i < G3; i += 512)
    biasl[i] = bih[i] + (i < 2 * HH ? bhh[i] : 0.f);

  // ---- stage A: all 4 kt slices, transpose+convert, swizzled ----
  // issue ALL 16 float4 loads first (latency overlap), then convert+write
  float4 xs[4][2][2];
#pragma unroll
  for (int kt = 0; kt < 4; kt++)
#pragma unroll
    for (int q = 0; q < 2; q++) {
      int idx = tid + 512 * q, sq = idx & 31, a = idx >> 5;
      const float* p = Xb + (size_t)(kt * 64 + 2 * a) * SSL + s0 + 4 * sq;
      xs[kt][q][0] = *(const float4*)p;
      xs[kt][q][1] = *(const float4*)(p + SSL);
    }
#pragma unroll
  for (int kt = 0; kt < 4; kt++)
#pragma unroll
    for (int q = 0; q < 2; q++) {
      int idx = tid + 512 * q, sq = idx & 31, a = idx >> 5;
      int c = a >> 2, d = a & 3;
#pragma unroll
      for (int r = 0; r < 4; r++) {
        int s = 4 * sq + r;
        int sw = (s + (s >> 3)) & 7;
        unsigned int u =
            (unsigned int)f2bf(((const float*)&xs[kt][q][0])[r]) |
            ((unsigned int)f2bf(((const float*)&xs[kt][q][1])[r]) << 16);
        *(unsigned int*)(Al + s * 256 + kt * 64 + ((c ^ sw) * 8) + d * 2) = u;
      }
    }

  // ---- stage B for jb=0 ----
  {
    uint4 wv[8];
#pragma unroll
    for (int p = 0; p < 8; p++) {
      int cid = tid + 512 * p, j = cid >> 5, c = cid & 31;
      wv[p] = *(const uint4*)(Wb + (size_t)(0 * 128 + j) * HH + c * 8);
    }
#pragma unroll
    for (int p = 0; p < 8; p++) {
      int cid = tid + 512 * p, j = cid >> 5, c = cid & 31;
      int sw = (j + (j >> 3)) & 7;
      *(uint4*)(Bl + j * 256 + (c >> 3) * 64 + (((c & 7) ^ sw) * 8)) = wv[p];
    }
  }
  __syncthreads();

  // ---- hoist A fragments: af[mt][kkk], reused for all 6 j-tiles ----
  short8 af[4][8];
#pragma unroll
  for (int mt = 0; mt < 4; mt++) {
    int s = wm * 64 + mt * 16 + n16;
    int sw = (s + (s >> 3)) & 7;
#pragma unroll
    for (int kkk = 0; kkk < 8; kkk++) {
      int kt = kkk >> 1, c3 = (kkk & 1) * 4 + quad;
      af[mt][kkk] = *(const short8*)(Al + s * 256 + kt * 64 + ((c3 ^ sw) * 8));
    }
  }

  for (int jb = 0; jb < 6; jb++) {
    // per-thread bias for epilogue cols
    float bb0 = biasl[jb * 128 + wn * 32 + 0 * 16 + n16];
    float bb1 = biasl[jb * 128 + wn * 32 + 1 * 16 + n16];

    f32x4 acc[4][2];
#pragma unroll
    for (int mt = 0; mt < 4; mt++)
#pragma unroll
      for (int nt = 0; nt < 2; nt++) acc[mt][nt] = f32x4{0.f, 0.f, 0.f, 0.f};

#pragma unroll
    for (int kkk = 0; kkk < 8; kkk++) {
      short8 bfr[2];
      int kt = kkk >> 1, c3 = (kkk & 1) * 4 + quad;
#pragma unroll
      for (int nt = 0; nt < 2; nt++) {
        int j = wn * 32 + nt * 16 + n16;
        int sw = (j + (j >> 3)) & 7;
        bfr[nt] = *(const short8*)(Bl + j * 256 + kt * 64 + ((c3 ^ sw) * 8));
      }
#pragma unroll
      for (int mt = 0; mt < 4; mt++)
#pragma unroll
        for (int nt = 0; nt < 2; nt++)
          acc[mt][nt] = __builtin_amdgcn_mfma_f32_16x16x32_bf16(af[mt][kkk], bfr[nt], acc[mt][nt], 0, 0, 0);
    }
    __syncthreads();   // MFMA B-reads drained before epilogue/next B-stage

    // ---- epilogue: two 64-row halves through bf16 LDS, coalesced stores ----
#pragma unroll
    for (int c = 0; c < 2; c++) {
      if (wm == c) {
#pragma unroll
        for (int mt = 0; mt < 4; mt++)
#pragma unroll
          for (int nt = 0; nt < 2; nt++) {
            float bb = nt ? bb1 : bb0;
#pragma unroll
            for (int r = 0; r < 4; r++)
              Dl[mt * 16 + quad * 4 + r][wn * 32 + nt * 16 + n16] =
                  f2bf(acc[mt][nt][r] + bb);
          }
      }
      __syncthreads();
      {
        int row = tid >> 3, seg = tid & 7;
        short8 v0 = *(const short8*)&Dl[row][seg * 16];
        short8 v1 = *(const short8*)&Dl[row][seg * 16 + 8];
        size_t go = ((size_t)(b * SSL + s0 + c * 64 + row)) * G3 + jb * 128 + seg * 16;
        *(short8*)(gi + go) = v0;
        *(short8*)(gi + go + 8) = v1;
      }
      __syncthreads();   // Dl reads done before next half / next jb writes
    }

    // ---- stage B for next jb ----
    if (jb < 5) {
      uint4 wv[8];
#pragma unroll
      for (int p = 0; p < 8; p++) {
        int cid = tid + 512 * p, j = cid >> 5, c = cid & 31;
        wv[p] = *(const uint4*)(Wb + (size_t)((jb + 1) * 128 + j) * HH + c * 8);
      }
#pragma unroll
      for (int p = 0; p < 8; p++) {
        int cid = tid + 512 * p, j = cid >> 5, c = cid & 31;
        int sw = (j + (j >> 3)) & 7;
        *(uint4*)(Bl + j * 256 + (c >> 3) * 64 + (((c & 7) ^ sw) * 8)) = wv[p];
      }
      __syncthreads();
    }
  }
}

// ---------------------------------------------------------------------------
// Kernel 2: persistent GRU scan. 64 blocks x 4 rows, 256 thr, 1 wave/SIMD.
// (R7 version, unchanged: in-register gates via replica-lane trick; one LDS
// roundtrip + one barrier per step.)
// ---------------------------------------------------------------------------
__global__ __launch_bounds__(256, 1) void gru_scan(
    const float* __restrict__ tree, const int* __restrict__ mask,
    const unsigned short* __restrict__ wfrag, const float* __restrict__ bhh,
    const unsigned short* __restrict__ gi, float* __restrict__ out)
{
  // slot(kt,b,q) = kt*17 + b*4 + q (16B units); 17-pad spreads banks
  __shared__ __align__(16) unsigned short hbuf[2][1088];
  __shared__ int lsum[4];

  const int tid  = threadIdx.x;
  const int lane = tid & 63;
  const int w    = tid >> 6;
  const int n16  = lane & 15;
  const int quad = lane >> 4;
  const int b    = n16 & 3;          // batch row owned by this lane
  const int rep  = n16 >> 2;         // replica index -> owns mt tile = rep
  const int brow0 = blockIdx.x * 4;
  const int jbase = w * 64 + rep * 16 + quad * 4;  // 4 owned j's

  if (tid < 4) lsum[tid] = 0;

  // initial h (lane-resident, f32)
  f32x4 h4 = *(const f32x4*)(tree + (size_t)(brow0 + b) * HH + jbase);

  // h write slot: kt=jbase>>5, q=(jbase>>3)&3, half=(quad&1)*4
  const int wslot = ((w * 2 + (rep >> 1)) * 17 + b * 4 + ((rep & 1) * 2 + (quad >> 1))) * 8
                  + (quad & 1) * 4;
  {
    unsigned long long u =
        (unsigned long long)((unsigned)f2bf(h4[0]) | ((unsigned)f2bf(h4[1]) << 16)) |
        ((unsigned long long)((unsigned)f2bf(h4[2]) | ((unsigned)f2bf(h4[3]) << 16)) << 32);
    *(unsigned long long*)&hbuf[0][wslot] = u;
  }
  {
    const int* mp = mask + (size_t)(brow0 + w) * SSL + lane * 8;
    int4 a = *(const int4*)mp;
    int4 c = *(const int4*)(mp + 4);
    atomicAdd(&lsum[w], a.x + a.y + a.z + a.w + c.x + c.y + c.z + c.w);
  }

  // W fragments: g=0,1 -> AGPR (64 frags = 256 AGPR); g=2 -> VGPR (128 VGPR)
  short8 awA[2][4][8];
  short8 awV[4][8];
#pragma unroll
  for (int g = 0; g < 2; g++)
#pragma unroll
    for (int mt = 0; mt < 4; mt++)
#pragma unroll
      for (int kt = 0; kt < 8; kt++) {
        int F = ((w * 3 + g) * 4 + mt) * 8 + kt;
        awA[g][mt][kt] = *(const short8*)(wfrag + ((size_t)F * 64 + lane) * 8);
      }
#pragma unroll
  for (int mt = 0; mt < 4; mt++)
#pragma unroll
    for (int kt = 0; kt < 8; kt++) {
      int F = ((w * 3 + 2) * 4 + mt) * 8 + kt;
      awV[mt][kt] = *(const short8*)(wfrag + ((size_t)F * 64 + lane) * 8);
    }
  // Pin: opaque to remat; forces register class (R5 lesson).
#pragma unroll
  for (int g = 0; g < 2; g++)
#pragma unroll
    for (int mt = 0; mt < 4; mt++)
#pragma unroll
      for (int kt = 0; kt < 8; kt++)
        asm volatile("" : "+a"(awA[g][mt][kt]));
#pragma unroll
  for (int mt = 0; mt < 4; mt++)
#pragma unroll
    for (int kt = 0; kt < 8; kt++)
      asm volatile("" : "+v"(awV[mt][kt]));

  f32x4 bh4 = *(const f32x4*)(bhh + 2 * HH + jbase);

  // per-lane gi stream: batch row b, j's = jbase..jbase+3, 3 gates (8B each)
  const unsigned short* gip = gi + (size_t)(brow0 + b) * SSL * G3 + jbase;
  unsigned long long gA[3], gB[3];
#pragma unroll
  for (int g = 0; g < 3; g++) gA[g] = *(const unsigned long long*)(gip + (size_t)0 * G3 + g * HH);
#pragma unroll
  for (int g = 0; g < 3; g++) gB[g] = *(const unsigned long long*)(gip + (size_t)1 * G3 + g * HH);

  __syncthreads();
  int mylast = lsum[b] - 1; if (mylast < 0) mylast = 0;

  auto step = [&](int t, unsigned long long* gv) {
    const int cb = t & 1, nb = cb ^ 1;
    unsigned long long g0 = gv[0], g1 = gv[1], g2 = gv[2];

    // hb fragments first (starts LDS latency early)
    const unsigned short* hp = &hbuf[cb][0] + ((n16 & 3) * 4 + quad) * 8;
    short8 hb[8];
#pragma unroll
    for (int kt = 0; kt < 8; kt++)
      hb[kt] = *(const short8*)(hp + kt * (17 * 8));

    // prefetch gi for t+2 (covered by ~1 full step; no vmcnt drain at barrier)
    int tn = (t + 2 < SSL) ? t + 2 : SSL - 1;
    gv[0] = *(const unsigned long long*)(gip + (size_t)tn * G3 + 0 * HH);
    gv[1] = *(const unsigned long long*)(gip + (size_t)tn * G3 + 1 * HH);
    gv[2] = *(const unsigned long long*)(gip + (size_t)tn * G3 + 2 * HH);

    // ---- MFMA: 96 per wave, 6 independent chains per pass; select own tile ----
    f32x4 selR, selZ, selN;
#pragma unroll
    for (int mp = 0; mp < 2; mp++) {
      const int m0 = 2 * mp, m1 = 2 * mp + 1;
      f32x4 ar0 = f32x4{0.f, 0.f, 0.f, 0.f}, az0 = ar0, an0 = ar0;
      f32x4 ar1 = ar0, az1 = ar0, an1 = ar0;
#pragma unroll
      for (int kt = 0; kt < 8; kt++) {
        ar0 = __builtin_amdgcn_mfma_f32_16x16x32_bf16(awA[0][m0][kt], hb[kt], ar0, 0, 0, 0);
        ar1 = __builtin_amdgcn_mfma_f32_16x16x32_bf16(awA[0][m1][kt], hb[kt], ar1, 0, 0, 0);
        az0 = __builtin_amdgcn_mfma_f32_16x16x32_bf16(awA[1][m0][kt], hb[kt], az0, 0, 0, 0);
        az1 = __builtin_amdgcn_mfma_f32_16x16x32_bf16(awA[1][m1][kt], hb[kt], az1, 0, 0, 0);
        an0 = __builtin_amdgcn_mfma_f32_16x16x32_bf16(awV[m0][kt],    hb[kt], an0, 0, 0, 0);
        an1 = __builtin_amdgcn_mfma_f32_16x16x32_bf16(awV[m1][kt],    hb[kt], an1, 0, 0, 0);
      }
      if (mp == 0) {
        selR = (rep == 0) ? ar0 : ar1;   // rep 2,3 garbage, fixed next pass
        selZ = (rep == 0) ? az0 : az1;
        selN = (rep == 0) ? an0 : an1;
      } else {
        selR = (rep == 2) ? ar0 : ((rep == 3) ? ar1 : selR);
        selZ = (rep == 2) ? az0 : ((rep == 3) ? az1 : selZ);
        selN = (rep == 2) ? an0 : ((rep == 3) ? an1 : selN);
      }
    }

    // ---- gates in-register: 4 (j,b) elements per lane ----
#pragma unroll
    for (int e = 0; e < 4; e++) {
      float gr = bf2f((unsigned short)((g0 >> (16 * e)) & 0xFFFFull));
      float gz = bf2f((unsigned short)((g1 >> (16 * e)) & 0xFFFFull));
      float gn = bf2f((unsigned short)((g2 >> (16 * e)) & 0xFFFFull));
      float r = __builtin_amdgcn_rcpf(1.f + __expf(-(selR[e] + gr)));
      float z = __builtin_amdgcn_rcpf(1.f + __expf(-(selZ[e] + gz)));
      float a = gn + r * (selN[e] + bh4[e]);
      float nn = 1.f - 2.f * __builtin_amdgcn_rcpf(__expf(2.f * a) + 1.f);
      h4[e] = nn + z * (h4[e] - nn);
    }
    {
      unsigned long long u =
          (unsigned long long)((unsigned)f2bf(h4[0]) | ((unsigned)f2bf(h4[1]) << 16)) |
          ((unsigned long long)((unsigned)f2bf(h4[2]) | ((unsigned)f2bf(h4[3]) << 16)) << 32);
      *(unsigned long long*)&hbuf[nb][wslot] = u;
    }
    if (t == mylast) {   // per-lane predicate (last unmasked timestep of batch b)
      *(f32x4*)(out + (size_t)(brow0 + b) * HH + jbase) = h4;
    }
    sync_step();
  };

  for (int t = 0; t < SSL; t += 2) {
    step(t, gA);
    step(t + 1, gB);
  }
}

extern "C" void kernel_launch(void* const* d_in, const int* in_sizes, int n_in,
                              void* d_out, int out_size, void* d_ws, size_t ws_size,
                              hipStream_t stream) {
  const float* tree = (const float*)d_in[0];
  const float* seq  = (const float*)d_in[1];
  const int*   mask = (const int*)d_in[2];
  const float* Wih  = (const float*)d_in[3];
  const float* Whh  = (const float*)d_in[4];
  const float* bih  = (const float*)d_in[5];
  const float* bhh  = (const float*)d_in[6];
  float* out = (float*)d_out;

  unsigned short* gi      = (unsigned short*)d_ws;                       // 201,326,592 B
  unsigned short* wih_bf  = (unsigned short*)((char*)d_ws + 201326592);  // 393,216 B
  unsigned short* whh_frag= (unsigned short*)((char*)d_ws + 201719808);  // 393,216 B

  prep_pack<<<192, 256, 0, stream>>>(Wih, Whh, wih_bf, whh_frag);
  gi_gemm<<<1024, 512, 0, stream>>>(seq, wih_bf, bih, bhh, gi);
  gru_scan<<<64, 256, 0, stream>>>(tree, mask, whh_frag, bhh, gi, out);
}